// Round 7
// baseline (4176.374 us; speedup 1.0000x reference)
//
#include <hip/hip_runtime.h>

// Wave-role-split forward 3rd-order jet propagation through the 9-layer tanh MLP.
// Each 64-point group is handled by a PAIR of waves:
//   role A (even wave): comps {v, x, y, t, xt, yt}         -- self-contained chain
//   role B (odd  wave): comps {xx, xy, yy, xxx, xxy, xyy, yyy} -- needs f, sx, sy from A (via LDS)
// Both roles alias one h[7][20] register array -> peak ~170 VGPR -> 3 waves/SIMD
// (vs. monolithic 260+ floats -> 256-VGPR encoding cap + spill + 1 wave/SIMD).
// Layer 0 is folded into the generic layer: first-order pre-acts = W0 weights, higher = 0.

namespace {
constexpr int HN = 20;

__device__ __forceinline__ float fast_tanh(float v) {
    float e = __expf(2.0f * v);      // saturates: +inf -> 1, -inf -> -1
    return 1.0f - 2.0f / (e + 1.0f);
}

template<int NCOMP, bool BIAS>
__device__ __forceinline__ void matvec_inplace(float (&h)[7][HN],
                                               const float* __restrict__ W,
                                               const float* __restrict__ bb) {
#pragma unroll
    for (int c = 0; c < NCOMP; ++c) {
        float tmp[HN];
#pragma unroll
        for (int j = 0; j < HN; ++j) {
            float acc = (BIAS && c == 0) ? bb[j] : 0.0f;
#pragma unroll
            for (int k = 0; k < HN; ++k)
                acc = fmaf(W[j*HN+k], h[c][k], acc);
            tmp[j] = acc;
        }
#pragma unroll
        for (int j = 0; j < HN; ++j) h[c][j] = tmp[j];
    }
}
} // namespace

__global__ __launch_bounds__(256, 3)
void ns_pinn_split(const float* __restrict__ gx, const float* __restrict__ gy,
                   const float* __restrict__ gt,
                   const float* __restrict__ W0, const float* __restrict__ b0,
                   const float* __restrict__ Wh, const float* __restrict__ bh,
                   const float* __restrict__ W9, const float* __restrict__ b9,
                   const float* __restrict__ lam1, const float* __restrict__ lam2,
                   float* __restrict__ out, int n)
{
    // lane-stride-1 innermost -> conflict-free (2 lanes/bank is free on CDNA4)
    __shared__ float shf[2][HN][64];
    __shared__ float shx[2][HN][64];
    __shared__ float shy[2][HN][64];

    const int tid   = threadIdx.x;
    const int lane  = tid & 63;
    const int wave  = tid >> 6;
    const int pair  = wave >> 1;         // 0..1: two independent 64-pt groups per block
    const bool roleA = (wave & 1) == 0;
    const int p = blockIdx.x * 128 + pair * 64 + lane;   // n % 128 == 0 (262144)

    float h[7][HN];   // role A uses rows 0..5, role B rows 0..6 (disjoint branches share regs)

    for (int l = 0; l < 9; ++l) {
        // ---- phase 1: per-role affine (pre-activation jet comps of this layer) ----
        if (l == 0) {
            if (roleA) {
                const float xi = gx[p], yi = gy[p], ti = gt[p];
#pragma unroll
                for (int j = 0; j < HN; ++j) {
                    const float w0 = W0[j*3+0], w1 = W0[j*3+1], w2 = W0[j*3+2];
                    h[0][j] = fmaf(w0, xi, fmaf(w1, yi, fmaf(w2, ti, b0[j])));
                    h[1][j] = w0;       // sx
                    h[2][j] = w1;       // sy
                    h[3][j] = w2;       // st
                    h[4][j] = 0.0f;     // sxt
                    h[5][j] = 0.0f;     // syt
                }
            } else {
#pragma unroll
                for (int c = 0; c < 7; ++c)
#pragma unroll
                    for (int j = 0; j < HN; ++j) h[c][j] = 0.0f;   // all 2nd/3rd pre-acts are 0
            }
        } else {
            const float* W  = Wh + (l-1)*HN*HN;
            const float* bb = bh + (l-1)*HN;
            if (roleA) matvec_inplace<6, true >(h, W, bb);
            else       matvec_inplace<7, false>(h, W, nullptr);
        }

        // ---- phase 1b: role A tanh-jet + publish f, sx, sy ----
        if (roleA) {
#pragma unroll
            for (int j = 0; j < HN; ++j) {
                const float sv = h[0][j], sx = h[1][j], sy = h[2][j], st = h[3][j],
                            sxt = h[4][j], syt = h[5][j];
                const float f  = fast_tanh(sv);
                const float g1 = 1.0f - f*f;
                const float g2 = -2.0f*f*g1;
                shf[pair][j][lane] = f;
                shx[pair][j][lane] = sx;
                shy[pair][j][lane] = sy;
                h[0][j] = f;
                h[1][j] = g1*sx; h[2][j] = g1*sy; h[3][j] = g1*st;
                h[4][j] = fmaf(g2, sx*st, g1*sxt);
                h[5][j] = fmaf(g2, sy*st, g1*syt);
            }
        }
        __syncthreads();

        // ---- phase 2: role B tanh-jet using A's f, sx, sy ----
        if (!roleA) {
#pragma unroll
            for (int j = 0; j < HN; ++j) {
                const float f  = shf[pair][j][lane];
                const float sx = shx[pair][j][lane];
                const float sy = shy[pair][j][lane];
                const float g1 = 1.0f - f*f;
                const float g2 = -2.0f*f*g1;
                const float g3 = -2.0f*(g1*g1 + f*g2);
                const float sxx = h[0][j], sxy = h[1][j], syy = h[2][j],
                            sxxx = h[3][j], sxxy = h[4][j], sxyy = h[5][j], syyy = h[6][j];
                h[0][j] = fmaf(g2, sx*sx, g1*sxx);
                h[1][j] = fmaf(g2, sx*sy, g1*sxy);
                h[2][j] = fmaf(g2, sy*sy, g1*syy);
                h[3][j] = g3*sx*sx*sx + 3.0f*g2*sx*sxx + g1*sxxx;
                h[4][j] = g3*sx*sx*sy + g2*(2.0f*sx*sxy + sy*sxx) + g1*sxxy;
                h[5][j] = g3*sx*sy*sy + g2*(2.0f*sy*sxy + sx*syy) + g1*sxyy;
                h[6][j] = g3*sy*sy*sy + 3.0f*g2*sy*syy + g1*syyy;
            }
        }
        __syncthreads();   // protect shf/shx/shy from next layer's A-writes
    }

    // ---- epilogue: psi head (row 0 of W9), p head (row 1) ----
    if (!roleA) {
#pragma unroll
        for (int c = 0; c < 7; ++c) {    // q_xx, q_xy, q_yy, q_xxx, q_xxy, q_xyy, q_yyy
            float acc = 0.0f;
#pragma unroll
            for (int k = 0; k < HN; ++k) acc = fmaf(W9[k], h[c][k], acc);
            shf[pair][c][lane] = acc;
        }
    }
    __syncthreads();
    if (roleA) {
        float qx = 0.0f, qy = 0.0f, qxt = 0.0f, qyt = 0.0f;
        float pv = b9[1], px = 0.0f, py = 0.0f;
#pragma unroll
        for (int k = 0; k < HN; ++k) {
            const float w9 = W9[k], wp = W9[HN + k];
            qx  = fmaf(w9, h[1][k], qx);
            qy  = fmaf(w9, h[2][k], qy);
            qxt = fmaf(w9, h[4][k], qxt);
            qyt = fmaf(w9, h[5][k], qyt);
            pv  = fmaf(wp, h[0][k], pv);
            px  = fmaf(wp, h[1][k], px);
            py  = fmaf(wp, h[2][k], py);
        }
        const float q_xx  = shf[pair][0][lane];
        const float q_xy  = shf[pair][1][lane];
        const float q_yy  = shf[pair][2][lane];
        const float q_xxx = shf[pair][3][lane];
        const float q_xxy = shf[pair][4][lane];
        const float q_xyy = shf[pair][5][lane];
        const float q_yyy = shf[pair][6][lane];

        const float l1 = lam1[0], l2 = lam2[0];
        const float u    = qy;        // psi_y
        const float v    = -qx;       // -psi_x
        const float u_x  = q_xy,  u_y  = q_yy,  u_t  = qyt;
        const float u_xx = q_xxy, u_yy = q_yyy;
        const float v_x  = -q_xx, v_y  = -q_xy, v_t  = -qxt;
        const float v_xx = -q_xxx, v_yy = -q_xyy;

        const float fo = u_t + l1*(u*u_x + v*u_y) + px - l2*(u_xx + u_yy);
        const float go = v_t + l1*(u*v_x + v*v_y) + py - l2*(v_xx + v_yy);

        float* o = out + (size_t)p * 5;
        o[0] = u; o[1] = v; o[2] = pv; o[3] = fo; o[4] = go;
    }
}

extern "C" void kernel_launch(void* const* d_in, const int* in_sizes, int n_in,
                              void* d_out, int out_size, void* d_ws, size_t ws_size,
                              hipStream_t stream)
{
    const float* x    = (const float*)d_in[0];
    const float* y    = (const float*)d_in[1];
    const float* t    = (const float*)d_in[2];
    const float* W0   = (const float*)d_in[3];
    const float* b0   = (const float*)d_in[4];
    const float* Wh   = (const float*)d_in[5];
    const float* bh   = (const float*)d_in[6];
    const float* W9   = (const float*)d_in[7];
    const float* b9   = (const float*)d_in[8];
    const float* lam1 = (const float*)d_in[9];
    const float* lam2 = (const float*)d_in[10];
    const int n = in_sizes[0];
    float* outp = (float*)d_out;

    const int block = 256;                  // 4 waves = 2 role-pairs = 128 points
    const int grid  = (n + 127) / 128;      // n = 262144 -> 2048 blocks
    hipLaunchKernelGGL(ns_pinn_split, dim3(grid), dim3(block), 0, stream,
                       x, y, t, W0, b0, Wh, bh, W9, b9, lam1, lam2, outp, n);
}

// Round 8
// 2215.132 us; speedup vs baseline: 1.8854x; 1.8854x over previous
//
#include <hip/hip_runtime.h>

// Monolithic 3rd-order jet propagation, one thread per point, with the 3
// t-chain components {t, xt, yt} held in a LANE-PRIVATE LDS slice instead of
// registers. Resident register state: 10 comps x 20 neurons = 200 floats
// (0:v 1:x 2:y 3:xx 4:xy 5:yy 6:xxx 7:xxy 8:xyy 9:yyy), + 20-reg matvec tmp.
// Total ~245 VGPR -> 2 waves/SIMD (vs 290 floats -> 256+AGPR -> 1 wave/SIMD).
// LDS layout [wave][comp][k][lane]: lane-stride-1, 2 lanes/bank = conflict-free;
// slices are lane-private -> NO barriers anywhere.

namespace {
constexpr int HN = 20;

__device__ __forceinline__ float fast_tanh(float v) {
    float e = __expf(2.0f * v);      // saturates: +inf -> 1, -inf -> -1
    return 1.0f - 2.0f / (e + 1.0f);
}
}

__global__ __launch_bounds__(256, 2)
void ns_pinn_lds(const float* __restrict__ gx, const float* __restrict__ gy,
                 const float* __restrict__ gt,
                 const float* __restrict__ W0, const float* __restrict__ b0,
                 const float* __restrict__ Wh, const float* __restrict__ bh,
                 const float* __restrict__ W9, const float* __restrict__ b9,
                 const float* __restrict__ lam1, const float* __restrict__ lam2,
                 float* __restrict__ out, int n)
{
    __shared__ float hld[4][3][HN][64];   // [wave][tcomp][neuron][lane] = 61440 B

    const int tid  = threadIdx.x;
    const int lane = tid & 63;
    const int wv   = tid >> 6;
    const int p    = blockIdx.x * 256 + tid;    // n % 256 == 0
    if (p >= n) return;

    float h[10][HN];   // resident jet comps

    // ---- layer 0: pre-acts are (affine, w0, w1, w2, 0...0); run generic jet ----
    {
        const float xi = gx[p], yi = gy[p], ti = gt[p];
#pragma unroll
        for (int j = 0; j < HN; ++j) {
            const float w0 = W0[j*3+0], w1 = W0[j*3+1], w2 = W0[j*3+2];
            const float sv = fmaf(w0, xi, fmaf(w1, yi, fmaf(w2, ti, b0[j])));
            const float f  = fast_tanh(sv);
            const float g1 = 1.0f - f*f;
            const float g2 = -2.0f*f*g1;
            const float g3 = -2.0f*(g1*g1 + f*g2);
            h[0][j] = f;
            h[1][j] = g1*w0;  h[2][j] = g1*w1;
            h[3][j] = g2*w0*w0; h[4][j] = g2*w0*w1; h[5][j] = g2*w1*w1;
            h[6][j] = g3*w0*w0*w0; h[7][j] = g3*w0*w0*w1;
            h[8][j] = g3*w0*w1*w1; h[9][j] = g3*w1*w1*w1;
            hld[wv][0][j][lane] = g1*w2;        // t
            hld[wv][1][j][lane] = g2*w0*w2;     // xt
            hld[wv][2][j][lane] = g2*w1*w2;     // yt
        }
    }

    // ---- 8 hidden layers ----
    for (int l = 0; l < 8; ++l) {
        const float* __restrict__ W  = Wh + l*HN*HN;
        const float* __restrict__ bb = bh + l*HN;

        // resident comps: in-place matvec via 20-reg tmp
#pragma unroll
        for (int c = 0; c < 10; ++c) {
            float tmp[HN];
#pragma unroll
            for (int j = 0; j < HN; ++j) {
                float acc = (c == 0) ? bb[j] : 0.0f;
#pragma unroll
                for (int k = 0; k < HN; ++k)
                    acc = fmaf(W[j*HN+k], h[c][k], acc);
                tmp[j] = acc;
            }
#pragma unroll
            for (int j = 0; j < HN; ++j) h[c][j] = tmp[j];
        }
        // LDS comps: load 20, matvec to 20 accs, store 20 (reads precede writes)
#pragma unroll
        for (int c = 0; c < 3; ++c) {
            float vin[HN];
#pragma unroll
            for (int k = 0; k < HN; ++k) vin[k] = hld[wv][c][k][lane];
            float tmp[HN];
#pragma unroll
            for (int j = 0; j < HN; ++j) {
                float acc = 0.0f;
#pragma unroll
                for (int k = 0; k < HN; ++k)
                    acc = fmaf(W[j*HN+k], vin[k], acc);
                tmp[j] = acc;
            }
#pragma unroll
            for (int j = 0; j < HN; ++j) hld[wv][c][j][lane] = tmp[j];
        }

        // tanh jet per neuron (in place; t-comps round-trip through LDS)
#pragma unroll
        for (int j = 0; j < HN; ++j) {
            const float sv  = h[0][j], sx  = h[1][j], sy  = h[2][j],
                        sxx = h[3][j], sxy = h[4][j], syy = h[5][j],
                        sxxx= h[6][j], sxxy= h[7][j], sxyy= h[8][j], syyy= h[9][j];
            const float st  = hld[wv][0][j][lane];
            const float sxt = hld[wv][1][j][lane];
            const float syt = hld[wv][2][j][lane];
            const float f  = fast_tanh(sv);
            const float g1 = 1.0f - f*f;
            const float g2 = -2.0f*f*g1;
            const float g3 = -2.0f*(g1*g1 + f*g2);
            h[0][j] = f;
            h[1][j] = g1*sx; h[2][j] = g1*sy;
            h[3][j] = fmaf(g2, sx*sx, g1*sxx);
            h[4][j] = fmaf(g2, sx*sy, g1*sxy);
            h[5][j] = fmaf(g2, sy*sy, g1*syy);
            h[6][j] = g3*sx*sx*sx + 3.0f*g2*sx*sxx + g1*sxxx;
            h[7][j] = g3*sx*sx*sy + g2*(2.0f*sx*sxy + sy*sxx) + g1*sxxy;
            h[8][j] = g3*sx*sy*sy + g2*(2.0f*sy*sxy + sx*syy) + g1*sxyy;
            h[9][j] = g3*sy*sy*sy + 3.0f*g2*sy*syy + g1*syyy;
            hld[wv][0][j][lane] = g1*st;
            hld[wv][1][j][lane] = fmaf(g2, sx*st, g1*sxt);
            hld[wv][2][j][lane] = fmaf(g2, sy*st, g1*syt);
        }
    }

    // ---- output heads ----
    float qx=0.f, qy=0.f, qxx=0.f, qxy=0.f, qyy=0.f,
          qxxx=0.f, qxxy=0.f, qxyy=0.f, qyyy=0.f,
          qxt=0.f, qyt=0.f, pv=b9[1], px=0.f, py=0.f;
#pragma unroll
    for (int k = 0; k < HN; ++k) {
        const float w9 = W9[k], wp = W9[HN + k];
        qx   = fmaf(w9, h[1][k], qx);
        qy   = fmaf(w9, h[2][k], qy);
        qxx  = fmaf(w9, h[3][k], qxx);
        qxy  = fmaf(w9, h[4][k], qxy);
        qyy  = fmaf(w9, h[5][k], qyy);
        qxxx = fmaf(w9, h[6][k], qxxx);
        qxxy = fmaf(w9, h[7][k], qxxy);
        qxyy = fmaf(w9, h[8][k], qxyy);
        qyyy = fmaf(w9, h[9][k], qyyy);
        qxt  = fmaf(w9, hld[wv][1][k][lane], qxt);
        qyt  = fmaf(w9, hld[wv][2][k][lane], qyt);
        pv   = fmaf(wp, h[0][k], pv);
        px   = fmaf(wp, h[1][k], px);
        py   = fmaf(wp, h[2][k], py);
    }

    const float l1 = lam1[0], l2 = lam2[0];
    const float u    = qy;          // psi_y
    const float v    = -qx;         // -psi_x
    const float u_x  = qxy,  u_y  = qyy,  u_t  = qyt;
    const float u_xx = qxxy, u_yy = qyyy;
    const float v_x  = -qxx, v_y  = -qxy, v_t  = -qxt;
    const float v_xx = -qxxx, v_yy = -qxyy;

    const float fo = u_t + l1*(u*u_x + v*u_y) + px - l2*(u_xx + u_yy);
    const float go = v_t + l1*(u*v_x + v*v_y) + py - l2*(v_xx + v_yy);

    float* o = out + (size_t)p * 5;
    o[0] = u; o[1] = v; o[2] = pv; o[3] = fo; o[4] = go;
}

extern "C" void kernel_launch(void* const* d_in, const int* in_sizes, int n_in,
                              void* d_out, int out_size, void* d_ws, size_t ws_size,
                              hipStream_t stream)
{
    const float* x    = (const float*)d_in[0];
    const float* y    = (const float*)d_in[1];
    const float* t    = (const float*)d_in[2];
    const float* W0   = (const float*)d_in[3];
    const float* b0   = (const float*)d_in[4];
    const float* Wh   = (const float*)d_in[5];
    const float* bh   = (const float*)d_in[6];
    const float* W9   = (const float*)d_in[7];
    const float* b9   = (const float*)d_in[8];
    const float* lam1 = (const float*)d_in[9];
    const float* lam2 = (const float*)d_in[10];
    const int n = in_sizes[0];
    float* outp = (float*)d_out;

    const int block = 256;
    const int grid  = (n + block - 1) / block;
    hipLaunchKernelGGL(ns_pinn_lds, dim3(grid), dim3(block), 0, stream,
                       x, y, t, W0, b0, Wh, bh, W9, b9, lam1, lam2, outp, n);
}